// Round 1
// 261.087 us; speedup vs baseline: 1.0007x; 1.0007x over previous
//
#include <hip/hip_runtime.h>

// SlotFillingCoachModel: ragged slot-span mean pooling + linear classifier.
// out[b,n,l] = (1/cnt) * sum_{r=beg..beg+len} hs[b,r,:] . W[:,l] + bias[l]
//
// R4: Phase-1 ragged sum rewritten as a fully-unrolled branchless 8-deep load
// (clamped row index + fmac mask) -> all span-row loads issue independently,
// ONE HBM latency round trip per work item instead of up to 4 dependent ones.
// prep_wt reads made coalesced (consecutive lanes read consecutive n).

#define BS    64
#define SEQ   1024
#define DIM   800
#define NSLOT 64
#define NLAB  72
#define SPB   8               // slots per block
#define NC    (DIM / 4)       // 200 float4 per row
#define PS    808             // pool LDS row stride (bf16 elems): 2-way banks, 16B-aligned
#define NTROW 80              // WT rows in ws (72 real + 8 zero)
#define KK    (DIM / 32)      // 25 MFMA k-steps
#define MAXS  8               // MAX_SPAN

typedef __attribute__((ext_vector_type(8))) short short8;   // bf16 A/B frag (4 VGPRs)
typedef __attribute__((ext_vector_type(4))) float float4v;  // fp32 C/D frag

static __device__ inline unsigned short f2bf(float f) {
    unsigned u = __builtin_bit_cast(unsigned, f);
    u += 0x7fffu + ((u >> 16) & 1u);          // round-to-nearest-even
    return (unsigned short)(u >> 16);
}

// ---- prep: WT[n][k] = bf16(W[k][n]), rows 72..79 zeroed ----
// i = k*NTROW + n: consecutive lanes -> consecutive n -> coalesced W reads.
// Writes are scattered 2B stores but tiny (128 KB total) and fire-and-forget.
__global__ void prep_wt_kernel(const float* __restrict__ W, unsigned short* __restrict__ wt) {
    int i = blockIdx.x * 256 + threadIdx.x;
    if (i >= DIM * NTROW) return;
    int k = i / NTROW;
    int n = i - k * NTROW;
    float v = (n < NLAB) ? W[k * NLAB + n] : 0.0f;
    wt[(size_t)n * DIM + k] = f2bf(v);
}

__global__ __launch_bounds__(320, 3) void slot_clf_kernel(
    const float*          __restrict__ hs,      // (BS, SEQ, DIM)
    const int*            __restrict__ begins,  // (BS, NSLOT)
    const int*            __restrict__ lens,    // (BS, NSLOT)
    const unsigned short* __restrict__ wt,      // (NTROW, DIM) bf16, transposed W
    const float*          __restrict__ bias,    // (NLAB)
    float*                __restrict__ out)     // (BS, NSLOT, NLAB)
{
    __shared__ unsigned short poolb[16 * PS];   // 25.9 KB, rows 8..15 zero (M-pad)
    __shared__ int s_begin[SPB];
    __shared__ int s_count[SPB];

    const int t  = threadIdx.x;
    const int b  = blockIdx.x >> 3;
    const int n0 = (blockIdx.x & 7) * SPB;      // first slot of this block

    if (t < SPB) {
        int idx = b * NSLOT + n0 + t;
        s_begin[t] = begins[idx];
        s_count[t] = lens[idx] + 1;             // inclusive end -> cnt in 1..8
    }
    // zero M-pad rows 8..15 (keep MFMA inputs finite)
    {
        unsigned* pz = (unsigned*)(poolb + 8 * PS);
        for (int i = t; i < 8 * PS / 2; i += 320) pz[i] = 0u;
    }
    __syncthreads();

    // ---- Phase 1: ragged mean-pool into bf16 LDS ----
    // Branchless: always issue 8 independent float4 loads (row clamped to cnt-1),
    // mask the accumulate. Clamped duplicates hit the same L1/L2 line -> no extra
    // HBM traffic; all loads of one work item are in flight together.
    for (int i = t; i < SPB * NC; i += 320) {   // exactly 5 iterations
        int s = i / NC;
        int c = i - s * NC;
        int beg = s_begin[s];
        int cnt = s_count[s];
        const float4* rowp = (const float4*)(hs + ((size_t)b * SEQ + beg) * DIM) + c;
        float ax = 0.f, ay = 0.f, az = 0.f, aw = 0.f;
        #pragma unroll
        for (int r = 0; r < MAXS; ++r) {
            int rr = (r < cnt) ? r : (cnt - 1);       // clamp: address always valid
            float4 v = rowp[(size_t)rr * NC];
            float m = (r < cnt) ? 1.0f : 0.0f;        // mask the tail
            ax += v.x * m; ay += v.y * m; az += v.z * m; aw += v.w * m;
        }
        float inv = 1.0f / (float)cnt;
        ushort4 pk;
        pk.x = f2bf(ax * inv);
        pk.y = f2bf(ay * inv);
        pk.z = f2bf(az * inv);
        pk.w = f2bf(aw * inv);
        *(ushort4*)(poolb + s * PS + 4 * c) = pk;   // 8B store, 8B-aligned
    }
    __syncthreads();

    // ---- Phase 2: logits via MFMA. wave w <-> label tile w (n = 16w .. 16w+15) ----
    const int wave = t >> 6;        // 0..4
    const int lane = t & 63;
    const int col  = lane & 15;     // = n_local (B/C col), also A row m for loads
    const int quad = lane >> 4;     // k-group: k = quad*8 + j

    const int n = wave * 16 + col;  // global label (>=72 on tile 4 -> zero rows)
    // A-frag: poolb[m=col][32*kk + 8*quad + j]
    const short8* ap = (const short8*)(poolb + col * PS + 8 * quad);
    // B-frag: wt[n][32*kk + 8*quad + j]
    const short8* bp = (const short8*)(wt + (size_t)n * DIM + 8 * quad);

    float4v acc = {0.f, 0.f, 0.f, 0.f};
    #pragma unroll 5
    for (int kk = 0; kk < KK; ++kk) {
        short8 a   = ap[4 * kk];    // k-step stride = 32 shorts = 4 short8
        short8 bfr = bp[4 * kk];
        acc = __builtin_amdgcn_mfma_f32_16x16x32_bf16(a, bfr, acc, 0, 0, 0);
    }

    // C/D layout: col = lane&15 (label), row m = quad*4 + reg (slot, valid m<8)
    if (n < NLAB) {
        float bv = bias[n];
        float* outb = out + ((size_t)b * NSLOT + n0) * NLAB + n;
        #pragma unroll
        for (int r = 0; r < 4; ++r) {
            int m = quad * 4 + r;
            if (m < SPB) outb[(size_t)m * NLAB] = acc[r] + bv;
        }
    }
}

extern "C" void kernel_launch(void* const* d_in, const int* in_sizes, int n_in,
                              void* d_out, int out_size, void* d_ws, size_t ws_size,
                              hipStream_t stream) {
    const float* hs     = (const float*)d_in[0];
    const int*   begins = (const int*)  d_in[1];
    const int*   lens   = (const int*)  d_in[2];
    const float* W      = (const float*)d_in[3];
    const float* bias   = (const float*)d_in[4];
    float*       out    = (float*)d_out;
    unsigned short* wt  = (unsigned short*)d_ws;   // 80*800*2 = 128 KB of ws

    prep_wt_kernel<<<dim3((NTROW * DIM + 255) / 256), dim3(256), 0, stream>>>(W, wt);
    slot_clf_kernel<<<dim3(BS * (NSLOT / SPB)), dim3(320), 0, stream>>>(
        hs, begins, lens, wt, bias, out);
}